// Round 7
// baseline (626.388 us; speedup 1.0000x reference)
//
#include <hip/hip_runtime.h>
#include <hip/hip_bf16.h>

typedef __bf16 bf16x8 __attribute__((ext_vector_type(8)));
typedef float f32x4 __attribute__((ext_vector_type(4)));
typedef short s16x8 __attribute__((ext_vector_type(8)));
typedef short s16x4 __attribute__((ext_vector_type(4)));

#define NTOK 49
#define CDIM 96
#define KS_S 104   // Ks row stride (ushort), 208B
#define VT_S 56    // VVT row stride (ushort), 112B
#define BN_S 136   // bounce row stride (ushort), 272B
#define GRID 768   // 3 blocks/CU x 256 CUs, all resident
#define LOG2E 1.4426950408889634f

#if __has_builtin(__builtin_amdgcn_exp2f)
#define EXP2F(x) __builtin_amdgcn_exp2f(x)
#else
#define EXP2F(x) exp2f(x)
#endif

#define DRAIN() do { asm volatile("s_waitcnt lgkmcnt(0)" ::: "memory"); \
                     __builtin_amdgcn_sched_barrier(0); } while (0)

__device__ __forceinline__ unsigned short f2bf(float f) {
  __hip_bfloat16 h = __float2bfloat16(f);
  return __builtin_bit_cast(unsigned short, h);
}

__device__ __forceinline__ bf16x8 cvt8(float4 a, float4 b) {
  s16x8 r;
  r[0] = (short)f2bf(a.x); r[1] = (short)f2bf(a.y);
  r[2] = (short)f2bf(a.z); r[3] = (short)f2bf(a.w);
  r[4] = (short)f2bf(b.x); r[5] = (short)f2bf(b.y);
  r[6] = (short)f2bf(b.z); r[7] = (short)f2bf(b.w);
  return __builtin_bit_cast(bf16x8, r);
}

// d_ws layout:
//   ushort[0      .. 9216 )  wqT    [oc 96][ic 96]  (bf16 bits)
//   ushort[9216   .. 27648)  wkvT   [oc 192][ic 96]
//   ushort[27648  .. 36864)  wprojT [oc 96][ic 96]
//   byte 73728: float biasf[3][49][64]  (rpb * log2e, cols 49..63 = 0)
__global__ void prep(const float* __restrict__ wq, const float* __restrict__ wkv,
                     const float* __restrict__ wproj, const float* __restrict__ rpb,
                     const int* __restrict__ relidx, unsigned short* __restrict__ wsT,
                     float* __restrict__ biasf) {
  const int total = 36864 + 3 * 49 * 64;
  for (int i = blockIdx.x * 256 + threadIdx.x; i < total; i += gridDim.x * 256) {
    if (i < 9216) {
      int oc = i / 96, ic = i - oc * 96;
      wsT[i] = f2bf(wq[ic * 96 + oc]);
    } else if (i < 27648) {
      int j = i - 9216; int oc = j / 96, ic = j - oc * 96;
      wsT[i] = f2bf(wkv[ic * 192 + oc]);
    } else if (i < 36864) {
      int j = i - 27648; int oc = j / 96, ic = j - oc * 96;
      wsT[i] = f2bf(wproj[ic * 96 + oc]);
    } else {
      int j = i - 36864; int h = j / 3136; int rc = j - h * 3136;
      int r = rc >> 6, c = rc & 63;
      biasf[j] = (c < 49) ? rpb[relidx[r * 49 + c] * 3 + h] * LOG2E : 0.f;
    }
  }
}

// Persistent fused kernel: grid-stride over windows, 2 barriers per window.
// Per iteration: cvt staged regs -> Q/KV proj -> SYNC -> prefetch next window's
// x/v (18 float4, latency hidden under attention) -> R5 head-batched attention
// (in-register softmax, bounce ping-pong, fp32 oacc) -> store -> SYNC.
__launch_bounds__(256, 3)
__global__ void attn_persist(const float* __restrict__ xg, const float* __restrict__ vg,
                             const float* __restrict__ bq, const float* __restrict__ bkv,
                             const float* __restrict__ bproj,
                             const unsigned short* __restrict__ wsT,
                             const float* __restrict__ biasf,
                             float* __restrict__ outg, int nwin) {
  // LDS (bytes): [0,10192) Ks[49][104] (rows 49..63 bleed-read -> masked)
  //              [10192,20944) VVT[96][56] (v^T; cols 49.. garbage -> vmask)
  //              [20944,38352) bounce[4 waves][16][136]
  __shared__ __align__(16) unsigned char smem[38352];
  unsigned short* Ks  = (unsigned short*)smem;
  unsigned short* VVT = (unsigned short*)(smem + 10192);

  const int tid = threadIdx.x, lane = tid & 63, wv = tid >> 6;
  const int c16 = lane & 15, g4 = lane >> 4;
  const int q0 = (wv == 0) ? 0 : (wv == 1) ? 16 : (wv == 2) ? 32 : 33;
  unsigned short* bnc = (unsigned short*)(smem + 20944) + wv * (16 * BN_S);

  // KV-proj task: wave = (K/V half, token-tile pair)
  const int mp = wv & 1;
  const bool isK = (wv < 2);
  const int m0 = mp ? 32 : 0;
  const int m1 = mp ? 33 : 16;

  const size_t WSTRIDE = NTOK * CDIM;
  const float* xq  = xg + (size_t)(q0 + c16) * CDIM;
  const float* vq0 = vg + (size_t)(m0 + c16) * CDIM;
  const float* vq1 = vg + (size_t)(m1 + c16) * CDIM;

  const int q = q0 + c16;
  const bool store_ok = (wv < 3) || (c16 == 15);
  s16x8 vmask;
#pragma unroll
  for (int j = 0; j < 8; ++j)
    vmask[j] = (short)(((32 + g4 * 8 + j) < 49) ? 0xFFFF : 0x0000);

  const float scale = 0.2550348742f;  // 32^-0.5 * log2(e)

  // register staging for next window's x/v (18 float4)
  float4 px[6], pv0[6], pv1[6];
  auto prefetch = [&](int w) {
    const float* xr = xq  + (size_t)w * WSTRIDE;
    const float* v0 = vq0 + (size_t)w * WSTRIDE;
    const float* v1 = vq1 + (size_t)w * WSTRIDE;
#pragma unroll
    for (int k = 0; k < 3; ++k) {
      const int off = k * 32 + g4 * 8;
      px[2*k]    = *(const float4*)(xr + off);
      px[2*k+1]  = *(const float4*)(xr + off + 4);
      pv0[2*k]   = *(const float4*)(v0 + off);
      pv0[2*k+1] = *(const float4*)(v0 + off + 4);
      pv1[2*k]   = *(const float4*)(v1 + off);
      pv1[2*k+1] = *(const float4*)(v1 + off + 4);
    }
  };

  int win = blockIdx.x;
  if (win < nwin) prefetch(win);

  for (; win < nwin; win += GRID) {
    // ---- convert staged floats -> bf16 fragments ----
    bf16x8 xf[3], vf0[3], vf1[3];
#pragma unroll
    for (int k = 0; k < 3; ++k) {
      xf[k]  = cvt8(px[2*k],  px[2*k+1]);
      vf0[k] = cvt8(pv0[2*k], pv0[2*k+1]);
      vf1[k] = cvt8(pv1[2*k], pv1[2*k+1]);
    }

    // ---- Q projection (own tile) -> bounce cols 0..95 ----
#pragma unroll
    for (int nt = 0; nt < 6; ++nt) {
      f32x4 acc = {0, 0, 0, 0};
      const int ocl = nt * 16 + c16;
#pragma unroll
      for (int k = 0; k < 3; ++k) {
        bf16x8 b = *(const bf16x8*)(wsT + ocl * 96 + k * 32 + g4 * 8);
        acc = __builtin_amdgcn_mfma_f32_16x16x32_bf16(xf[k], b, acc, 0, 0, 0);
      }
      float bias = bq[ocl];
#pragma unroll
      for (int r = 0; r < 4; ++r)
        bnc[(4 * g4 + r) * BN_S + ocl] = f2bf((acc[r] + bias) * scale);
    }

    // ---- K/V projection: own oc-half for two token tiles ----
#pragma unroll
    for (int nt = 0; nt < 6; ++nt) {
      const int ocl = (isK ? 0 : 96) + nt * 16 + c16;
      f32x4 a0 = {0, 0, 0, 0}, a1 = {0, 0, 0, 0};
#pragma unroll
      for (int k = 0; k < 3; ++k) {
        bf16x8 b = *(const bf16x8*)(wsT + 9216 + ocl * 96 + k * 32 + g4 * 8);
        a0 = __builtin_amdgcn_mfma_f32_16x16x32_bf16(vf0[k], b, a0, 0, 0, 0);
        a1 = __builtin_amdgcn_mfma_f32_16x16x32_bf16(vf1[k], b, a1, 0, 0, 0);
      }
      float bias = bkv[ocl];
      if (isK) {
#pragma unroll
        for (int r = 0; r < 4; ++r)
          Ks[(m0 + 4 * g4 + r) * KS_S + ocl] = f2bf(a0[r] + bias);
#pragma unroll
        for (int r = 0; r < 4; ++r)
          Ks[(m1 + 4 * g4 + r) * KS_S + ocl] = f2bf(a1[r] + bias);
      } else {
        int dim = ocl - 96;
        s16x4 p0;
#pragma unroll
        for (int r = 0; r < 4; ++r) p0[r] = (short)f2bf(a0[r] + bias);
        *(s16x4*)(VVT + dim * VT_S + (m0 + 4 * g4)) = p0;
        if (mp == 0) {
          s16x4 p1;
#pragma unroll
          for (int r = 0; r < 4; ++r) p1[r] = (short)f2bf(a1[r] + bias);
          *(s16x4*)(VVT + dim * VT_S + (16 + 4 * g4)) = p1;
        } else {
#pragma unroll
          for (int r = 0; r < 4; ++r)
            VVT[dim * VT_S + 33 + 4 * g4 + r] = f2bf(a1[r] + bias);
        }
      }
    }
    __syncthreads();   // Ks/VVT + own Q bounce ready

    // ---- prefetch next window (latency hides under attention) ----
    if (win + GRID < nwin) prefetch(win + GRID);

    // ---- attention: 3 heads batched (R5-verified schedule) ----
    f32x4 oacc[6] = {{0,0,0,0},{0,0,0,0},{0,0,0,0},{0,0,0,0},{0,0,0,0},{0,0,0,0}};

    auto softmax_pw = [&](const f32x4* s, const f32x4* bv, int pcol) {
      float vals[16];
#pragma unroll
      for (int kt = 0; kt < 4; ++kt)
#pragma unroll
        for (int r = 0; r < 4; ++r) {
          int key = 16 * kt + 4 * g4 + r;
          vals[kt * 4 + r] = (kt < 3 || key < 49) ? (s[kt][r] + bv[kt][r]) : -1e30f;
        }
      float m8[8];
#pragma unroll
      for (int j = 0; j < 8; ++j) m8[j] = fmaxf(vals[j], vals[j + 8]);
      float ma = fmaxf(m8[0], m8[4]), mb = fmaxf(m8[1], m8[5]);
      float mc = fmaxf(m8[2], m8[6]), md = fmaxf(m8[3], m8[7]);
      float mx = fmaxf(fmaxf(ma, mb), fmaxf(mc, md));
      mx = fmaxf(mx, __shfl_xor(mx, 16, 64));
      mx = fmaxf(mx, __shfl_xor(mx, 32, 64));
      float e[16];
#pragma unroll
      for (int j = 0; j < 16; ++j) e[j] = EXP2F(vals[j] - mx);
      float s8[8];
#pragma unroll
      for (int j = 0; j < 8; ++j) s8[j] = e[j] + e[j + 8];
      float sa = s8[0] + s8[4], sb = s8[1] + s8[5], sc = s8[2] + s8[6], sd = s8[3] + s8[7];
      float sum = (sa + sb) + (sc + sd);
      sum += __shfl_xor(sum, 16, 64);
      sum += __shfl_xor(sum, 32, 64);
      float rinv = 1.0f / sum;
#pragma unroll
      for (int kt = 0; kt < 4; ++kt) {
        s16x4 p;
#pragma unroll
        for (int r = 0; r < 4; ++r) p[r] = (short)f2bf(e[kt * 4 + r] * rinv);
        *(s16x4*)(bnc + c16 * BN_S + pcol + 16 * kt + 4 * g4) = p;
      }
    };

    auto pv_out = [&](int h, int pcol, int ocol) {
      bf16x8 ap0 = *(const bf16x8*)(bnc + c16 * BN_S + pcol + g4 * 8);
      bf16x8 ap1 = *(const bf16x8*)(bnc + c16 * BN_S + pcol + 32 + g4 * 8);
#pragma unroll
      for (int dt = 0; dt < 2; ++dt) {
        int dim = h * 32 + dt * 16 + c16;
        bf16x8 bv0 = *(const bf16x8*)(VVT + dim * VT_S + g4 * 8);
        s16x8 b1 = *(const s16x8*)(VVT + dim * VT_S + 32 + g4 * 8);
        b1 &= vmask;
        f32x4 o = __builtin_amdgcn_mfma_f32_16x16x32_bf16(ap0, bv0, (f32x4){0,0,0,0}, 0, 0, 0);
        o = __builtin_amdgcn_mfma_f32_16x16x32_bf16(ap1, __builtin_bit_cast(bf16x8, b1), o, 0, 0, 0);
#pragma unroll
        for (int r = 0; r < 4; ++r)
          bnc[(4 * g4 + r) * BN_S + ocol + dt * 16 + c16] = f2bf(o[r]);
      }
    };

    auto oproj = [&](int h, int ocol) {
      bf16x8 bo = *(const bf16x8*)(bnc + c16 * BN_S + ocol + g4 * 8);
#pragma unroll
      for (int mt = 0; mt < 6; ++mt) {
        bf16x8 a = *(const bf16x8*)(wsT + 27648 + (mt * 16 + c16) * 96 + h * 32 + g4 * 8);
        oacc[mt] = __builtin_amdgcn_mfma_f32_16x16x32_bf16(a, bo, oacc[mt], 0, 0, 0);
      }
    };

    f32x4 b0v[4], b1v[4];
    {
      const float* br0 = biasf + q * 64 + 4 * g4;
      const float* br1 = biasf + (49 + q) * 64 + 4 * g4;
#pragma unroll
      for (int kt = 0; kt < 4; ++kt) {
        b0v[kt] = *(const f32x4*)(br0 + 16 * kt);
        b1v[kt] = *(const f32x4*)(br1 + 16 * kt);
      }
    }
    bf16x8 qf0 = *(const bf16x8*)(bnc + c16 * BN_S + g4 * 8);
    bf16x8 qf1 = *(const bf16x8*)(bnc + c16 * BN_S + 32 + g4 * 8);
    bf16x8 qf2 = *(const bf16x8*)(bnc + c16 * BN_S + 64 + g4 * 8);

    f32x4 s0[4], s1[4];
#pragma unroll
    for (int kt = 0; kt < 4; ++kt) {
      bf16x8 ak = *(const bf16x8*)(Ks + (16 * kt + c16) * KS_S + g4 * 8);
      s0[kt] = __builtin_amdgcn_mfma_f32_16x16x32_bf16(ak, qf0, (f32x4){0,0,0,0}, 0, 0, 0);
    }
#pragma unroll
    for (int kt = 0; kt < 4; ++kt) {
      bf16x8 ak = *(const bf16x8*)(Ks + (16 * kt + c16) * KS_S + 32 + g4 * 8);
      s1[kt] = __builtin_amdgcn_mfma_f32_16x16x32_bf16(ak, qf1, (f32x4){0,0,0,0}, 0, 0, 0);
    }
    softmax_pw(s0, b0v, 0);    // P0 -> 0..63
    softmax_pw(s1, b1v, 64);   // P1 -> 64..127

    f32x4 b2v[4];
    {
      const float* br2 = biasf + (98 + q) * 64 + 4 * g4;
#pragma unroll
      for (int kt = 0; kt < 4; ++kt) b2v[kt] = *(const f32x4*)(br2 + 16 * kt);
    }
    f32x4 s2[4];
#pragma unroll
    for (int kt = 0; kt < 4; ++kt) {
      bf16x8 ak = *(const bf16x8*)(Ks + (16 * kt + c16) * KS_S + 64 + g4 * 8);
      s2[kt] = __builtin_amdgcn_mfma_f32_16x16x32_bf16(ak, qf2, (f32x4){0,0,0,0}, 0, 0, 0);
    }

    DRAIN();                   // P0,P1 visible
    pv_out(0, 0, 0);           // P0 (0..63)   -> OUT0 0..31
    pv_out(1, 64, 32);         // P1 (64..127) -> OUT1 32..63
    softmax_pw(s2, b2v, 64);   // P2 -> 64..127 (P1 reads issued)

    DRAIN();                   // OUT0, OUT1, P2 visible
    oproj(0, 0);
    oproj(1, 32);
    pv_out(2, 64, 96);         // P2 (64..127) -> OUT2 96..127

    DRAIN();                   // OUT2 visible
    oproj(2, 96);

    // ---- store ----
    {
      float* orow = outg + (size_t)win * WSTRIDE + q * 96;
#pragma unroll
      for (int mt = 0; mt < 6; ++mt) {
        int oc0 = mt * 16 + g4 * 4;
        if (store_ok) {
          float4 bb = *(const float4*)(bproj + oc0);
          float4 o4;
          o4.x = oacc[mt][0] + bb.x; o4.y = oacc[mt][1] + bb.y;
          o4.z = oacc[mt][2] + bb.z; o4.w = oacc[mt][3] + bb.w;
          *(float4*)(orow + oc0) = o4;
        }
      }
    }
    __syncthreads();   // all waves done reading Ks/VVT before next iter's writes
  }
}

extern "C" void kernel_launch(void* const* d_in, const int* in_sizes, int n_in,
                              void* d_out, int out_size, void* d_ws, size_t ws_size,
                              hipStream_t stream) {
  const float* x     = (const float*)d_in[0];
  const float* v     = (const float*)d_in[1];
  const float* wq    = (const float*)d_in[2];
  const float* bq    = (const float*)d_in[3];
  const float* wkv   = (const float*)d_in[4];
  const float* bkv   = (const float*)d_in[5];
  const float* wproj = (const float*)d_in[6];
  const float* bproj = (const float*)d_in[7];
  const float* rpb   = (const float*)d_in[8];
  const int*   relidx= (const int*)d_in[9];
  float* out = (float*)d_out;
  unsigned short* wsT = (unsigned short*)d_ws;
  float* biasf = (float*)((char*)d_ws + 73728);
  int nwin = in_sizes[0] / (NTOK * CDIM);   // 8192

  hipLaunchKernelGGL(prep, dim3(181), dim3(256), 0, stream,
                     wq, wkv, wproj, rpb, relidx, wsT, biasf);
  hipLaunchKernelGGL(attn_persist, dim3(GRID), dim3(256), 0, stream,
                     x, v, bq, bkv, bproj, wsT, biasf, out, nwin);
}

// Round 8
// 253.895 us; speedup vs baseline: 2.4671x; 2.4671x over previous
//
#include <hip/hip_runtime.h>
#include <hip/hip_bf16.h>

typedef __bf16 bf16x8 __attribute__((ext_vector_type(8)));
typedef float f32x4 __attribute__((ext_vector_type(4)));
typedef short s16x8 __attribute__((ext_vector_type(8)));
typedef short s16x4 __attribute__((ext_vector_type(4)));

#define NTOK 49
#define CDIM 96
#define KS_S 104   // Ks row stride (ushort), 208B
#define VT_S 56    // VVT row stride (ushort), 112B
#define BN_S 136   // bounce row stride (ushort), 272B
#define LOG2E 1.4426950408889634f

#if __has_builtin(__builtin_amdgcn_exp2f)
#define EXP2F(x) __builtin_amdgcn_exp2f(x)
#else
#define EXP2F(x) exp2f(x)
#endif

#define DRAIN() do { asm volatile("s_waitcnt lgkmcnt(0)" ::: "memory"); \
                     __builtin_amdgcn_sched_barrier(0); } while (0)

__device__ __forceinline__ unsigned short f2bf(float f) {
  __hip_bfloat16 h = __float2bfloat16(f);
  return __builtin_bit_cast(unsigned short, h);
}

// single-instruction packed fp32->bf16 (RNE), per cdna guide T12 recipe
__device__ __forceinline__ unsigned int cvtpk(float lo, float hi) {
  unsigned int r;
  asm("v_cvt_pk_bf16_f32 %0, %1, %2" : "=v"(r) : "v"(lo), "v"(hi));
  return r;
}
__device__ __forceinline__ unsigned short f2bf_f(float f) {
  return (unsigned short)cvtpk(f, f);
}
__device__ __forceinline__ s16x4 pack4(float a, float b, float c, float d) {
  union { unsigned int u[2]; s16x4 v; } r;
  r.u[0] = cvtpk(a, b); r.u[1] = cvtpk(c, d);
  return r.v;
}

// load 8 consecutive floats from global, convert to bf16x8 (4 cvt_pk)
__device__ __forceinline__ bf16x8 ld_cvt8(const float* p) {
  float4 a = *(const float4*)p;
  float4 b = *(const float4*)(p + 4);
  union { unsigned int u[4]; bf16x8 v; } r;
  r.u[0] = cvtpk(a.x, a.y); r.u[1] = cvtpk(a.z, a.w);
  r.u[2] = cvtpk(b.x, b.y); r.u[3] = cvtpk(b.z, b.w);
  return r.v;
}

// d_ws layout:
//   ushort[0      .. 9216 )  wqT    [oc 96][ic 96]  (bf16 bits)
//   ushort[9216   .. 27648)  wkvT   [oc 192][ic 96]
//   ushort[27648  .. 36864)  wprojT [oc 96][ic 96]
//   byte 73728: float biasf[3][49][64]  (rpb * log2e, cols 49..63 = 0)
__global__ void prep(const float* __restrict__ wq, const float* __restrict__ wkv,
                     const float* __restrict__ wproj, const float* __restrict__ rpb,
                     const int* __restrict__ relidx, unsigned short* __restrict__ wsT,
                     float* __restrict__ biasf) {
  const int total = 36864 + 3 * 49 * 64;
  for (int i = blockIdx.x * 256 + threadIdx.x; i < total; i += gridDim.x * 256) {
    if (i < 9216) {
      int oc = i / 96, ic = i - oc * 96;
      wsT[i] = f2bf(wq[ic * 96 + oc]);
    } else if (i < 27648) {
      int j = i - 9216; int oc = j / 96, ic = j - oc * 96;
      wsT[i] = f2bf(wkv[ic * 192 + oc]);
    } else if (i < 36864) {
      int j = i - 27648; int oc = j / 96, ic = j - oc * 96;
      wsT[i] = f2bf(wproj[ic * 96 + oc]);
    } else {
      int j = i - 36864; int h = j / 3136; int rc = j - h * 3136;
      int r = rc >> 6, c = rc & 63;
      biasf[j] = (c < 49) ? rpb[relidx[r * 49 + c] * 3 + h] * LOG2E : 0.f;
    }
  }
}

// R5-verified fused structure + ILP: merged software-pipelined projection loop
// (double-buffered weight frags), explicit operand preloads before each MFMA
// cluster, cvt_pk conversions, launch_bounds(256,3) so registers are available.
__launch_bounds__(256, 3)
__global__ void attn_fused(const float* __restrict__ xg, const float* __restrict__ vg,
                           const float* __restrict__ bq, const float* __restrict__ bkv,
                           const float* __restrict__ bproj,
                           const unsigned short* __restrict__ wsT,
                           const float* __restrict__ biasf,
                           float* __restrict__ outg) {
  // LDS (bytes): [0,10192) Ks[49][104] (rows 49..63 bleed-read -> masked)
  //              [10192,20944) VVT[96][56] (v^T; cols 49.. unwritten -> vmask)
  //              [20944,38352) bounce[4 waves][16][136]
  __shared__ __align__(16) unsigned char smem[38352];
  unsigned short* Ks  = (unsigned short*)smem;
  unsigned short* VVT = (unsigned short*)(smem + 10192);

  const int tid = threadIdx.x, lane = tid & 63, wv = tid >> 6;
  const int c16 = lane & 15, g4 = lane >> 4;
  const int win = blockIdx.x;
  const int q0 = (wv == 0) ? 0 : (wv == 1) ? 16 : (wv == 2) ? 32 : 33;
  unsigned short* bnc = (unsigned short*)(smem + 20944) + wv * (16 * BN_S);

  // KV-proj task: wave = (K/V half, token-tile pair)
  const int mp = wv & 1;
  const bool isK = (wv < 2);
  const int m0 = mp ? 32 : 0;
  const int m1 = mp ? 33 : 16;

  const float* base = xg + (size_t)win * (NTOK * CDIM);
  const float* vbase = vg + (size_t)win * (NTOK * CDIM);
  const float* xrow = base + (q0 + c16) * CDIM;
  const float* vrow0 = vbase + (m0 + c16) * CDIM;
  const float* vrow1 = vbase + (m1 + c16) * CDIM;

  // ---- direct global->reg fragment loads ----
  bf16x8 xf[3], vf0[3], vf1[3];
#pragma unroll
  for (int k = 0; k < 3; ++k) {
    xf[k]  = ld_cvt8(xrow  + k * 32 + g4 * 8);
    vf0[k] = ld_cvt8(vrow0 + k * 32 + g4 * 8);
    vf1[k] = ld_cvt8(vrow1 + k * 32 + g4 * 8);
  }

  // ---- biases hoisted (independent early loads) ----
  float bqv[6], bkvv[6];
#pragma unroll
  for (int nt = 0; nt < 6; ++nt) {
    bqv[nt]  = bq[nt * 16 + c16];
    bkvv[nt] = bkv[(isK ? 0 : 96) + nt * 16 + c16];
  }

  const float scale = 0.2550348742f;  // 32^-0.5 * log2(e)
  const unsigned short* wkvBase = wsT + 9216 + (isK ? 0 : 9216);

  // ---- merged Q + KV projection, software-pipelined weight loads ----
  {
    bf16x8 wqf[2][3], wkf[2][3];
#pragma unroll
    for (int k = 0; k < 3; ++k) {
      wqf[0][k] = *(const bf16x8*)(wsT     + c16 * 96 + k * 32 + g4 * 8);
      wkf[0][k] = *(const bf16x8*)(wkvBase + c16 * 96 + k * 32 + g4 * 8);
    }
#pragma unroll
    for (int nt = 0; nt < 6; ++nt) {
      const int cur = nt & 1, nxt = cur ^ 1;
      if (nt < 5) {
#pragma unroll
        for (int k = 0; k < 3; ++k) {
          wqf[nxt][k] = *(const bf16x8*)(wsT     + ((nt + 1) * 16 + c16) * 96 + k * 32 + g4 * 8);
          wkf[nxt][k] = *(const bf16x8*)(wkvBase + ((nt + 1) * 16 + c16) * 96 + k * 32 + g4 * 8);
        }
      }
      f32x4 aq = {0,0,0,0}, a0 = {0,0,0,0}, a1 = {0,0,0,0};
      __builtin_amdgcn_s_setprio(1);
#pragma unroll
      for (int k = 0; k < 3; ++k) {
        aq = __builtin_amdgcn_mfma_f32_16x16x32_bf16(xf[k],  wqf[cur][k], aq, 0, 0, 0);
        a0 = __builtin_amdgcn_mfma_f32_16x16x32_bf16(vf0[k], wkf[cur][k], a0, 0, 0, 0);
        a1 = __builtin_amdgcn_mfma_f32_16x16x32_bf16(vf1[k], wkf[cur][k], a1, 0, 0, 0);
      }
      __builtin_amdgcn_s_setprio(0);
      // Q store (own tile)
      {
        const int ocl = nt * 16 + c16;
        float bias = bqv[nt];
#pragma unroll
        for (int r = 0; r < 4; ++r)
          bnc[(4 * g4 + r) * BN_S + ocl] = f2bf_f((aq[r] + bias) * scale);
      }
      // K/V store
      {
        float bias = bkvv[nt];
        if (isK) {
          const int ocl = nt * 16 + c16;
#pragma unroll
          for (int r = 0; r < 4; ++r)
            Ks[(m0 + 4 * g4 + r) * KS_S + ocl] = f2bf_f(a0[r] + bias);
#pragma unroll
          for (int r = 0; r < 4; ++r)
            Ks[(m1 + 4 * g4 + r) * KS_S + ocl] = f2bf_f(a1[r] + bias);
        } else {
          const int dim = nt * 16 + c16;
          *(s16x4*)(VVT + dim * VT_S + (m0 + 4 * g4)) =
              pack4(a0[0] + bias, a0[1] + bias, a0[2] + bias, a0[3] + bias);
          if (mp == 0) {
            *(s16x4*)(VVT + dim * VT_S + (16 + 4 * g4)) =
                pack4(a1[0] + bias, a1[1] + bias, a1[2] + bias, a1[3] + bias);
          } else {
#pragma unroll
            for (int r = 0; r < 4; ++r)
              VVT[dim * VT_S + 33 + 4 * g4 + r] = f2bf_f(a1[r] + bias);
          }
        }
      }
    }
  }
  __syncthreads();   // the only block barrier

  // ---- attention: 3 heads batched (R5-verified schedule) ----
  const int q = q0 + c16;
  s16x8 vmask;
#pragma unroll
  for (int j = 0; j < 8; ++j)
    vmask[j] = (short)(((32 + g4 * 8 + j) < 49) ? 0xFFFF : 0x0000);

  f32x4 oacc[6] = {{0,0,0,0},{0,0,0,0},{0,0,0,0},{0,0,0,0},{0,0,0,0},{0,0,0,0}};

  auto softmax_pw = [&](const f32x4* s, const f32x4* bv, int pcol) {
    float vals[16];
#pragma unroll
    for (int kt = 0; kt < 4; ++kt)
#pragma unroll
      for (int r = 0; r < 4; ++r) {
        int key = 16 * kt + 4 * g4 + r;
        vals[kt * 4 + r] = (kt < 3 || key < 49) ? (s[kt][r] + bv[kt][r]) : -1e30f;
      }
    float m8[8];
#pragma unroll
    for (int j = 0; j < 8; ++j) m8[j] = fmaxf(vals[j], vals[j + 8]);
    float ma = fmaxf(m8[0], m8[4]), mb = fmaxf(m8[1], m8[5]);
    float mc = fmaxf(m8[2], m8[6]), md = fmaxf(m8[3], m8[7]);
    float mx = fmaxf(fmaxf(ma, mb), fmaxf(mc, md));
    mx = fmaxf(mx, __shfl_xor(mx, 16, 64));
    mx = fmaxf(mx, __shfl_xor(mx, 32, 64));
    float e[16];
#pragma unroll
    for (int j = 0; j < 16; ++j) e[j] = EXP2F(vals[j] - mx);
    float s8[8];
#pragma unroll
    for (int j = 0; j < 8; ++j) s8[j] = e[j] + e[j + 8];
    float sa = s8[0] + s8[4], sb = s8[1] + s8[5], sc = s8[2] + s8[6], sd = s8[3] + s8[7];
    float sum = (sa + sb) + (sc + sd);
    sum += __shfl_xor(sum, 16, 64);
    sum += __shfl_xor(sum, 32, 64);
    float rinv = 1.0f / sum;
#pragma unroll
    for (int kt = 0; kt < 4; ++kt)
      *(s16x4*)(bnc + c16 * BN_S + pcol + 16 * kt + 4 * g4) =
          pack4(e[kt*4] * rinv, e[kt*4+1] * rinv, e[kt*4+2] * rinv, e[kt*4+3] * rinv);
  };

  auto pv_out = [&](int h, int pcol, int ocol) {
    bf16x8 ap0 = *(const bf16x8*)(bnc + c16 * BN_S + pcol + g4 * 8);
    bf16x8 ap1 = *(const bf16x8*)(bnc + c16 * BN_S + pcol + 32 + g4 * 8);
    // preload both dt operand pairs before the MFMA cluster
    bf16x8 bva[2]; s16x8 bvb[2];
#pragma unroll
    for (int dt = 0; dt < 2; ++dt) {
      int dim = h * 32 + dt * 16 + c16;
      bva[dt] = *(const bf16x8*)(VVT + dim * VT_S + g4 * 8);
      s16x8 t = *(const s16x8*)(VVT + dim * VT_S + 32 + g4 * 8);
      bvb[dt] = t & vmask;
    }
    f32x4 o[2];
    __builtin_amdgcn_s_setprio(1);
#pragma unroll
    for (int dt = 0; dt < 2; ++dt) {
      o[dt] = __builtin_amdgcn_mfma_f32_16x16x32_bf16(ap0, bva[dt], (f32x4){0,0,0,0}, 0, 0, 0);
      o[dt] = __builtin_amdgcn_mfma_f32_16x16x32_bf16(ap1, __builtin_bit_cast(bf16x8, bvb[dt]), o[dt], 0, 0, 0);
    }
    __builtin_amdgcn_s_setprio(0);
#pragma unroll
    for (int dt = 0; dt < 2; ++dt)
#pragma unroll
      for (int r = 0; r < 4; ++r)
        bnc[(4 * g4 + r) * BN_S + ocol + dt * 16 + c16] = f2bf_f(o[dt][r]);
  };

  auto oproj = [&](int h, int ocol) {
    bf16x8 bo = *(const bf16x8*)(bnc + c16 * BN_S + ocol + g4 * 8);
    bf16x8 wa[6];
#pragma unroll
    for (int mt = 0; mt < 6; ++mt)
      wa[mt] = *(const bf16x8*)(wsT + 27648 + (mt * 16 + c16) * 96 + h * 32 + g4 * 8);
    __builtin_amdgcn_s_setprio(1);
#pragma unroll
    for (int mt = 0; mt < 6; ++mt)
      oacc[mt] = __builtin_amdgcn_mfma_f32_16x16x32_bf16(wa[mt], bo, oacc[mt], 0, 0, 0);
    __builtin_amdgcn_s_setprio(0);
  };

  f32x4 b0v[4], b1v[4];
  {
    const float* br0 = biasf + q * 64 + 4 * g4;
    const float* br1 = biasf + (49 + q) * 64 + 4 * g4;
#pragma unroll
    for (int kt = 0; kt < 4; ++kt) {
      b0v[kt] = *(const f32x4*)(br0 + 16 * kt);
      b1v[kt] = *(const f32x4*)(br1 + 16 * kt);
    }
  }
  bf16x8 qf0 = *(const bf16x8*)(bnc + c16 * BN_S + g4 * 8);
  bf16x8 qf1 = *(const bf16x8*)(bnc + c16 * BN_S + 32 + g4 * 8);
  bf16x8 qf2 = *(const bf16x8*)(bnc + c16 * BN_S + 64 + g4 * 8);

  // QK^T heads 0,1: preload K frags, then MFMA clusters
  f32x4 s0[4], s1[4];
  {
    bf16x8 ak0[4], ak1[4];
#pragma unroll
    for (int kt = 0; kt < 4; ++kt) {
      ak0[kt] = *(const bf16x8*)(Ks + (16 * kt + c16) * KS_S + g4 * 8);
      ak1[kt] = *(const bf16x8*)(Ks + (16 * kt + c16) * KS_S + 32 + g4 * 8);
    }
    __builtin_amdgcn_s_setprio(1);
#pragma unroll
    for (int kt = 0; kt < 4; ++kt)
      s0[kt] = __builtin_amdgcn_mfma_f32_16x16x32_bf16(ak0[kt], qf0, (f32x4){0,0,0,0}, 0, 0, 0);
#pragma unroll
    for (int kt = 0; kt < 4; ++kt)
      s1[kt] = __builtin_amdgcn_mfma_f32_16x16x32_bf16(ak1[kt], qf1, (f32x4){0,0,0,0}, 0, 0, 0);
    __builtin_amdgcn_s_setprio(0);
  }
  softmax_pw(s0, b0v, 0);    // P0 -> 0..63   (Q reads already issued)
  softmax_pw(s1, b1v, 64);   // P1 -> 64..127

  // QK^T head 2 + bias h2
  f32x4 b2v[4];
  {
    const float* br2 = biasf + (98 + q) * 64 + 4 * g4;
#pragma unroll
    for (int kt = 0; kt < 4; ++kt) b2v[kt] = *(const f32x4*)(br2 + 16 * kt);
  }
  f32x4 s2[4];
  {
    bf16x8 ak2[4];
#pragma unroll
    for (int kt = 0; kt < 4; ++kt)
      ak2[kt] = *(const bf16x8*)(Ks + (16 * kt + c16) * KS_S + 64 + g4 * 8);
    __builtin_amdgcn_s_setprio(1);
#pragma unroll
    for (int kt = 0; kt < 4; ++kt)
      s2[kt] = __builtin_amdgcn_mfma_f32_16x16x32_bf16(ak2[kt], qf2, (f32x4){0,0,0,0}, 0, 0, 0);
    __builtin_amdgcn_s_setprio(0);
  }

  DRAIN();                   // P0,P1 visible
  pv_out(0, 0, 0);           // P0 (0..63)   -> OUT0 0..31
  pv_out(1, 64, 32);         // P1 (64..127) -> OUT1 32..63
  softmax_pw(s2, b2v, 64);   // P2 -> 64..127 (P1 reads issued above)

  DRAIN();                   // OUT0, OUT1, P2 visible
  oproj(0, 0);
  oproj(1, 32);
  pv_out(2, 64, 96);         // P2 (64..127) -> OUT2 96..127 (after ap1 read)

  DRAIN();                   // OUT2 visible
  oproj(2, 96);

  // ---- store: lane holds out[oc=mt*16+4g4+r][token=q0+c16] ----
  {
    const bool store_ok = (wv < 3) || (c16 == 15);  // tile 3 only stores token 48
    float* orow = outg + (size_t)win * (NTOK * CDIM) + q * 96;
#pragma unroll
    for (int mt = 0; mt < 6; ++mt) {
      int oc0 = mt * 16 + g4 * 4;
      if (store_ok) {
        float4 bb = *(const float4*)(bproj + oc0);
        float4 o4;
        o4.x = oacc[mt][0] + bb.x; o4.y = oacc[mt][1] + bb.y;
        o4.z = oacc[mt][2] + bb.z; o4.w = oacc[mt][3] + bb.w;
        *(float4*)(orow + oc0) = o4;
      }
    }
  }
}

extern "C" void kernel_launch(void* const* d_in, const int* in_sizes, int n_in,
                              void* d_out, int out_size, void* d_ws, size_t ws_size,
                              hipStream_t stream) {
  const float* x     = (const float*)d_in[0];
  const float* v     = (const float*)d_in[1];
  const float* wq    = (const float*)d_in[2];
  const float* bq    = (const float*)d_in[3];
  const float* wkv   = (const float*)d_in[4];
  const float* bkv   = (const float*)d_in[5];
  const float* wproj = (const float*)d_in[6];
  const float* bproj = (const float*)d_in[7];
  const float* rpb   = (const float*)d_in[8];
  const int*   relidx= (const int*)d_in[9];
  float* out = (float*)d_out;
  unsigned short* wsT = (unsigned short*)d_ws;
  float* biasf = (float*)((char*)d_ws + 73728);
  int nwin = in_sizes[0] / (NTOK * CDIM);   // 8192

  hipLaunchKernelGGL(prep, dim3(181), dim3(256), 0, stream,
                     wq, wkv, wproj, rpb, relidx, wsT, biasf);
  hipLaunchKernelGGL(attn_fused, dim3(nwin), dim3(256), 0, stream,
                     x, v, bq, bkv, bproj, wsT, biasf, out);
}